// Round 15
// baseline (113.330 us; speedup 1.0000x reference)
//
#include <hip/hip_runtime.h>
#include <hip/hip_bf16.h>
#include <cstdint>
#include <cstddef>

// Problem constants
#define B_ 64
#define S_ 4096
#define D_ 256
#define BM 32                    // rows per block
#define NBLK (B_ * S_ / BM)      // 8192
#define BLKS_PER_B (S_ / BM)     // 128 blocks per batch

typedef __attribute__((ext_vector_type(8))) short short8;
typedef __attribute__((ext_vector_type(16))) float f32x16;
typedef __attribute__((ext_vector_type(4))) float f4;

__device__ __forceinline__ short f2bf(float f) {
  union { float f; uint32_t u; } v; v.f = f;
  uint32_t r = v.u + 0x7FFFu + ((v.u >> 16) & 1u);   // RNE
  return (short)(r >> 16);
}

__device__ __forceinline__ float fast_tanh(float z) {
  // tanh(z) = 1 - 2*rcp(e^{2z}+1); overflow-safe (R4/R5/R6/R14-proven)
  return 1.0f - 2.0f * __builtin_amdgcn_rcpf(__expf(2.0f * z) + 1.0f);
}

// Kernel 0: frag-pack W for mfma_32x32x16 B-operand.
// wtp[(((s*8)+cg)*64 + l)*8 + j] = bf16(W[k][n]),
//   k = s*16 + (l>>5)*8 + j,  n = cg*32 + (l&31).
// A wave's per-step B fragment = 64 lanes x 16B contiguous (1KB) in global.
__global__ void k_pack(const float* __restrict__ W, short* __restrict__ wtp) {
  int idx = blockIdx.x * 1024 + threadIdx.x;   // 64 blocks -> 65536
  int j = idx & 7, l = (idx >> 3) & 63, cg = (idx >> 9) & 7, s = idx >> 12;
  int k = s * 16 + ((l >> 5) << 3) + j;
  int n = cg * 32 + (l & 31);
  wtp[idx] = f2bf(W[k * 256 + n]);
}

// Kernel 1: fused GEMM(x@W)+tanh+dot(u) -> scores + per-block softmax
// partials (m,l) + context partial. grid NBLK, 512 thr = 8 waves.
// Wave = 32 rows x 32 cols (cg). acc = 16 VGPR; B = 64 VGPR (loaded once,
// static); A = 16KB swizzled LDS shared by all waves. K-loop: 16 x
// {ds_read_b128 + mfma_32x32x16}, NO barriers.
__global__ __launch_bounds__(512, 4)
void k_scores(const float* __restrict__ x, const short* __restrict__ wtp,
              const float* __restrict__ bias, const float* __restrict__ u,
              float* __restrict__ ws_scores, float* __restrict__ ws_m,
              float* __restrict__ ws_l, float* __restrict__ ws_c) {
  __shared__ __align__(16) char lsA[BM * 512];   // 16KB bf16, XOR-swizzled rows
  __shared__ float score_part[BM][9];            // +1 pad col
  __shared__ float e_lds[BM];

  const int tid  = threadIdx.x;
  const int bid  = blockIdx.x;
  const int m0   = bid * BM;
  const int lane = tid & 63;
  const int cg   = tid >> 6;       // wave id = col group (cols cg*32..+31)
  const int l31  = lane & 31;
  const int hi   = lane >> 5;

  // ---- stage A first (HBM, longest latency): thread -> row tid>>4, 16 f32
  const int srow = tid >> 4;
  const int sc0  = (tid & 15) * 16;
  const float* xs = x + (size_t)(m0 + srow) * D_ + sc0;
  f4 g0 = *(const f4*)(xs);
  f4 g1 = *(const f4*)(xs + 4);
  f4 g2 = *(const f4*)(xs + 8);
  f4 g3 = *(const f4*)(xs + 12);

  // ---- B frags (L2, frag-packed): 16 x b128 coalesced, into registers
  short8 b[16];
  const short* wb = wtp + cg * 512 + lane * 8;
#pragma unroll
  for (int s = 0; s < 16; ++s)
    b[s] = *(const short8*)(wb + s * 4096);

  const float bb = bias[cg * 32 + l31];
  const float uu = u[cg * 32 + l31];

  // cvt + write A tile (swizzled: byte bits 4-6 ^= row&7)
  {
    short8 s0, s1;
    s0[0]=f2bf(g0[0]); s0[1]=f2bf(g0[1]); s0[2]=f2bf(g0[2]); s0[3]=f2bf(g0[3]);
    s0[4]=f2bf(g1[0]); s0[5]=f2bf(g1[1]); s0[6]=f2bf(g1[2]); s0[7]=f2bf(g1[3]);
    s1[0]=f2bf(g2[0]); s1[1]=f2bf(g2[1]); s1[2]=f2bf(g2[2]); s1[3]=f2bf(g2[3]);
    s1[4]=f2bf(g3[0]); s1[5]=f2bf(g3[1]); s1[6]=f2bf(g3[2]); s1[7]=f2bf(g3[3]);
    const int sw = (srow & 7) << 4;
    *(short8*)&lsA[srow * 512 + ((sc0 * 2) ^ sw)]      = s0;
    *(short8*)&lsA[srow * 512 + ((sc0 * 2 + 16) ^ sw)] = s1;
  }
  __syncthreads();   // A staged (the only pre-loop barrier)

  f32x16 acc;
#pragma unroll
  for (int i = 0; i < 16; ++i) acc[i] = 0.f;

  // ---- barrier-free K-loop: 16 steps of K=16
  const int abase = l31 * 512;
  const int asw   = (l31 & 7) << 4;
#pragma unroll
  for (int s = 0; s < 16; ++s) {
    short8 af = *(const short8*)&lsA[abase + ((s * 32 + hi * 16) ^ asw)];
    acc = __builtin_amdgcn_mfma_f32_32x32x16_bf16(af, b[s], acc, 0, 0, 0);
  }

  // ---- epilogue: per-reg tanh + 32-lane butterfly col-sum
  float pr[16];
#pragma unroll
  for (int i = 0; i < 16; ++i) {
    float v = fast_tanh(acc[i] + bb) * uu;
#pragma unroll
    for (int m = 1; m < 32; m <<= 1) v += __shfl_xor(v, m);
    pr[i] = v;
  }
  if (l31 == 0) {
#pragma unroll
    for (int i = 0; i < 16; ++i) {
      int r = (i & 3) + 8 * (i >> 2) + 4 * hi;   // m74/m101 C-layout row
      score_part[r][cg] = pr[i];
    }
  }
  __syncthreads();

  if (tid < BM) {
    float s = 0.f;
#pragma unroll
    for (int c = 0; c < 8; ++c) s += score_part[tid][c];
    ws_scores[m0 + tid] = s;
    float mx = s;
#pragma unroll
    for (int m = 1; m < 32; m <<= 1) mx = fmaxf(mx, __shfl_xor(mx, m));
    float e = __expf(s - mx);
    e_lds[tid] = e;
    float l = e;
#pragma unroll
    for (int m = 1; m < 32; m <<= 1) l += __shfl_xor(l, m);
    if (tid == 0) { ws_m[bid] = mx; ws_l[bid] = l; }
  }
  __syncthreads();

  // context partial: thread owns column d = tid (<256); x tile is L1/L2-hot
  if (tid < D_) {
    float cacc = 0.f;
    const float* xp = x + (size_t)m0 * D_ + tid;
#pragma unroll 8
    for (int s = 0; s < BM; ++s) cacc = fmaf(e_lds[s], xp[(size_t)s * D_], cacc);
    ws_c[(size_t)bid * D_ + tid] = cacc;
  }
}

// Kernel 2 (fused combine+weights): grid B_ (64), 1024 thr, 128 partials/batch.
__global__ __launch_bounds__(1024)
void k_epi(const float* __restrict__ ws_m, const float* __restrict__ ws_l,
           const float* __restrict__ ws_c, const float* __restrict__ ws_scores,
           float* __restrict__ out_ctx, float* __restrict__ out_w) {
  __shared__ float mv[BLKS_PER_B], lv[BLKS_PER_B], fac[BLKS_PER_B], MLs[2];
  const int b = blockIdx.x, tid = threadIdx.x;

  if (tid < BLKS_PER_B) {
    mv[tid] = ws_m[b * BLKS_PER_B + tid];
    lv[tid] = ws_l[b * BLKS_PER_B + tid];
  }
  __syncthreads();
  if (tid < 64) {
    float m2 = fmaxf(mv[tid], mv[tid + 64]);
#pragma unroll
    for (int o = 1; o < 64; o <<= 1) m2 = fmaxf(m2, __shfl_xor(m2, o));
    if (tid == 0) MLs[0] = m2;
  }
  __syncthreads();
  const float M = MLs[0];
  if (tid < BLKS_PER_B) fac[tid] = __expf(mv[tid] - M);
  __syncthreads();
  if (tid < 64) {
    float L2 = fac[tid] * lv[tid] + fac[tid + 64] * lv[tid + 64];
#pragma unroll
    for (int o = 1; o < 64; o <<= 1) L2 += __shfl_xor(L2, o);
    if (tid == 0) MLs[1] = L2;
  }
  __syncthreads();
  const float invL = 1.0f / MLs[1];

  if (tid < D_) {
    float c = 0.f;
#pragma unroll 8
    for (int i = 0; i < BLKS_PER_B; ++i)
      c = fmaf(fac[i], ws_c[(size_t)(b * BLKS_PER_B + i) * D_ + tid], c);
    out_ctx[b * D_ + tid] = c * invL;
  }
#pragma unroll
  for (int r = 0; r < 4; ++r) {
    int s = r * 1024 + tid;
    out_w[b * S_ + s] = __expf(ws_scores[b * S_ + s] - M) * invL;
  }
}

extern "C" void kernel_launch(void* const* d_in, const int* in_sizes, int n_in,
                              void* d_out, int out_size, void* d_ws, size_t ws_size,
                              hipStream_t stream) {
  (void)in_sizes; (void)n_in; (void)out_size; (void)ws_size;
  const float* x    = (const float*)d_in[0];
  const float* W    = (const float*)d_in[1];
  const float* bias = (const float*)d_in[2];
  const float* u    = (const float*)d_in[3];
  float* out_ctx = (float*)d_out;                 // [64,256]
  float* out_w   = (float*)d_out + B_ * D_;       // [64,4096]

  char* ws = (char*)d_ws;
  short* wtp       = (short*)(ws + 0);            // 131072 B (frag-packed W)
  float* ws_scores = (float*)(ws + 131072);       // 1048576 B
  float* ws_m      = (float*)(ws + 1179648);      // 32768 B (8192 blocks)
  float* ws_l      = (float*)(ws + 1212416);      // 32768 B
  float* ws_c      = (float*)(ws + 1245184);      // 8388608 B (8192 x 256)

  hipLaunchKernelGGL(k_pack, dim3(64), dim3(1024), 0, stream, W, wtp);
  hipLaunchKernelGGL(k_scores, dim3(NBLK), dim3(512), 0, stream,
                     x, wtp, bias, u, ws_scores, ws_m, ws_l, ws_c);
  hipLaunchKernelGGL(k_epi, dim3(B_), dim3(1024), 0, stream,
                     ws_m, ws_l, ws_c, ws_scores, out_ctx, out_w);
}

// Round 17
// 113.178 us; speedup vs baseline: 1.0013x; 1.0013x over previous
//
#include <hip/hip_runtime.h>
#include <hip/hip_bf16.h>
#include <cstdint>
#include <cstddef>

// Problem constants
#define B_ 64
#define S_ 4096
#define D_ 256
#define BM 64                   // rows per block (4 waves x 16 rows)
#define BK 32                   // k-step
#define NBLK (B_ * S_ / BM)     // 4096
#define BLKS_PER_B (S_ / BM)    // 64

typedef __attribute__((ext_vector_type(8))) short short8;
typedef __attribute__((ext_vector_type(4))) float f32x4;
typedef __attribute__((ext_vector_type(4))) float f4;

__device__ __forceinline__ short f2bf(float f) {
  union { float f; uint32_t u; } v; v.f = f;
  uint32_t r = v.u + 0x7FFFu + ((v.u >> 16) & 1u);   // RNE
  return (short)(r >> 16);
}

__device__ __forceinline__ short f2bf_i(float f) {
  // compiler-visible RNE convert (no inline asm, no manual bit-twiddle)
  union { __hip_bfloat16 b; short s; } v;
  v.b = __float2bfloat16(f);
  return v.s;
}

__device__ __forceinline__ float fast_tanh(float z) {
  // tanh(z) = 1 - 2*rcp(e^{2z}+1); overflow-safe; rcp form PASSED R4/5/6/14
  return 1.0f - 2.0f * __builtin_amdgcn_rcpf(__expf(2.0f * z) + 1.0f);
}

__device__ __forceinline__ void gload_lds16(const short* g, short* l) {
  __builtin_amdgcn_global_load_lds(
      (const __attribute__((address_space(1))) int*)(g),
      (__attribute__((address_space(3))) int*)(l), 16, 0, 0);
}

// Kernel 0: Wt[n][k] = bf16(W[k][n]) via LDS tile transpose. grid 16, 1024 thr.
__global__ void k_pack(const float* __restrict__ W, short* __restrict__ wt) {
  __shared__ float tile[64][65];
  int t = blockIdx.x, ti = t >> 2, tj = t & 3;
  int tid = threadIdx.x;
#pragma unroll
  for (int i = 0; i < 4; ++i) {
    int idx = i * 1024 + tid;
    int r = idx >> 6, c = idx & 63;                 // r: k-local, c: n-local
    tile[c][r] = W[(ti * 64 + r) * 256 + tj * 64 + c];
  }
  __syncthreads();
#pragma unroll
  for (int i = 0; i < 4; ++i) {
    int idx = i * 1024 + tid;
    int r = idx >> 6, c = idx & 63;                 // r: n-local, c: k-local
    wt[(tj * 64 + r) * 256 + ti * 64 + c] = f2bf(tile[r][c]);
  }
}

// ---- k_scores helper macros (R14-proven pipeline) ---------------------------
#define WAITV(N) asm volatile("s_waitcnt vmcnt(" #N ")" ::: "memory")
#define FENCE()  asm volatile("" ::: "memory")

// Stage B k-step KC into lsB[BUF]: 16 KB, 4 x global_load_lds(16B) per thread.
#define STAGE(BUF, KC)                                                        \
  {                                                                           \
    _Pragma("unroll")                                                         \
    for (int i_ = 0; i_ < 4; ++i_) {                                          \
      int c_ = i_ * 256 + tid;                                                \
      int n_ = c_ >> 2, ko_ = (c_ & 3) * 8;                                   \
      gload_lds16(wt + n_ * 256 + (KC) * 32 + ko_, &lsB[BUF][c_ * 8]);        \
    }                                                                         \
  }

// One pipelined K-step (R14 structure; SINGLE DELTA: bf16 convert via
// compiler-visible __float2bfloat16 — NO inline asm, waitcnt tracking
// stays intact): stage(K+1), issue A(K+2), counted vmcnt, barriers, cvt, MFMA.
#define ITER(KC, VM, SCA, SCB, SLA, SLB, DOSTAGE, DOLOAD)                     \
  {                                                                           \
    if (DOSTAGE) STAGE(((KC) + 1) & 1, (KC) + 1);                             \
    if (DOLOAD) {                                                             \
      SLA = *(const f4*)(xrow + ((KC) + 2) * 32);                             \
      SLB = *(const f4*)(xrow + ((KC) + 2) * 32 + 4);                         \
    }                                                                         \
    WAITV(VM);                                                                \
    asm volatile("s_waitcnt lgkmcnt(0)" ::: "memory");                        \
    __builtin_amdgcn_sched_barrier(0);                                        \
    __builtin_amdgcn_s_barrier();                                             \
    FENCE();                                                                  \
    short8 fr_;                                                               \
    fr_[0]=f2bf_i(SCA[0]); fr_[1]=f2bf_i(SCA[1]); fr_[2]=f2bf_i(SCA[2]); fr_[3]=f2bf_i(SCA[3]); \
    fr_[4]=f2bf_i(SCB[0]); fr_[5]=f2bf_i(SCB[1]); fr_[6]=f2bf_i(SCB[2]); fr_[7]=f2bf_i(SCB[3]); \
    _Pragma("unroll")                                                         \
    for (int nf_ = 0; nf_ < 16; ++nf_) {                                      \
      short8 bfr_ = *(const short8*)&lsB[(KC) & 1][(nf_ * 16 + cl) * 32 + gr * 8]; \
      acc[nf_] = __builtin_amdgcn_mfma_f32_16x16x32_bf16(fr_, bfr_, acc[nf_], 0, 0, 0); \
    }                                                                         \
    FENCE();                                                                  \
    __builtin_amdgcn_s_barrier();                                             \
    FENCE();                                                                  \
  }

// Kernel 1: fused GEMM(x@W)+tanh+dot(u) -> scores; per-block softmax partials
// (m, l) and context partial. grid NBLK, 256 thr (4 waves, 16 rows each).
// B double-buffered in LDS, counted-vmcnt pipeline (R8/R14 schedule, proven).
__global__ __launch_bounds__(256, 3)
void k_scores(const float* __restrict__ x, const short* __restrict__ wt,
              const float* __restrict__ bias, const float* __restrict__ u,
              float* __restrict__ ws_scores, float* __restrict__ ws_m,
              float* __restrict__ ws_l, float* __restrict__ ws_c) {
  __shared__ __align__(16) short lsB[2][D_ * BK];   // 2 x 16 KB, linear (64B rows)
  __shared__ __align__(8) float bu[D_ * 2];         // (bias, u) pairs
  __shared__ float score_lds[BM];
  __shared__ float e_lds[BM];
  __shared__ float red_lds[1];

  const int tid  = threadIdx.x;
  const int bid  = blockIdx.x;
  const int m0   = bid * BM;
  const int lane = tid & 63;
  const int wv   = tid >> 6;       // 0..3 : 16-row group
  const int cl   = lane & 15;
  const int gr   = lane >> 4;      // 0..3

  // (bias,u) first: compiler drains their loads before the ds_write, keeping
  // the vmcnt queue empty when the pipelined loads start.  (R14 verbatim)
  bu[tid * 2]     = bias[tid];
  bu[tid * 2 + 1] = u[tid];

  f32x4 acc[16];
#pragma unroll
  for (int j = 0; j < 16; ++j) acc[j] = (f32x4){0.f, 0.f, 0.f, 0.f};

  const float* xrow = x + (size_t)(m0 + wv * 16 + cl) * D_ + gr * 8;

  // Prologue: queue = A(0)[2], stage(0)[4], A(1)[2]
  f4 s0a, s0b, s1a, s1b, s2a, s2b;
  s0a = *(const f4*)(xrow);       s0b = *(const f4*)(xrow + 4);
  STAGE(0, 0);
  s1a = *(const f4*)(xrow + 32);  s1b = *(const f4*)(xrow + 36);

  // Steady state: 8 outstanding (4 stage + 2+2 A) stay in flight across waits.
  ITER(0, 8, s0a, s0b, s2a, s2b, 1, 1)
  ITER(1, 8, s1a, s1b, s0a, s0b, 1, 1)
  ITER(2, 8, s2a, s2b, s1a, s1b, 1, 1)
  ITER(3, 8, s0a, s0b, s2a, s2b, 1, 1)
  ITER(4, 8, s1a, s1b, s0a, s0b, 1, 1)
  ITER(5, 8, s2a, s2b, s1a, s1b, 1, 1)
  ITER(6, 6, s0a, s0b, s0a, s0b, 1, 0)
  ITER(7, 0, s1a, s1b, s0a, s0b, 0, 0)

  // Epilogue: score[row] = sum_n tanh(acc[row][n] + b[n]) * u[n]  (R14 verbatim)
  float p0 = 0.f, p1 = 0.f, p2 = 0.f, p3 = 0.f;
#pragma unroll
  for (int nf = 0; nf < 16; ++nf) {
    float bb = bu[(nf * 16 + cl) * 2];
    float uu = bu[(nf * 16 + cl) * 2 + 1];
    p0 += fast_tanh(acc[nf][0] + bb) * uu;
    p1 += fast_tanh(acc[nf][1] + bb) * uu;
    p2 += fast_tanh(acc[nf][2] + bb) * uu;
    p3 += fast_tanh(acc[nf][3] + bb) * uu;
  }
#pragma unroll
  for (int m = 1; m < 16; m <<= 1) {
    p0 += __shfl_xor(p0, m);
    p1 += __shfl_xor(p1, m);
    p2 += __shfl_xor(p2, m);
    p3 += __shfl_xor(p3, m);
  }
  if (cl == 0) {
    int r = wv * 16 + gr * 4;
    score_lds[r + 0] = p0;
    score_lds[r + 1] = p1;
    score_lds[r + 2] = p2;
    score_lds[r + 3] = p3;
    ws_scores[m0 + r + 0] = p0;
    ws_scores[m0 + r + 1] = p1;
    ws_scores[m0 + r + 2] = p2;
    ws_scores[m0 + r + 3] = p3;
  }
  __syncthreads();
  // block max over 64 scores (wave 0)
  if (tid < 64) {
    float v = score_lds[tid];
#pragma unroll
    for (int m = 32; m >= 1; m >>= 1) v = fmaxf(v, __shfl_xor(v, m));
    if (tid == 0) red_lds[0] = v;
  }
  __syncthreads();
  float mb = red_lds[0];
  if (tid < BM) e_lds[tid] = __expf(score_lds[tid] - mb);
  __syncthreads();
  if (tid < 64) {
    float v = e_lds[tid];
#pragma unroll
    for (int m = 32; m >= 1; m >>= 1) v += __shfl_xor(v, m);
    if (tid == 0) { ws_m[bid] = mb; ws_l[bid] = v; }
  }
  // context partial: thread owns column d = tid; x tile is L1/L2-hot
  float cacc = 0.f;
  const float* xp = x + (size_t)m0 * D_ + tid;
#pragma unroll 4
  for (int s = 0; s < BM; ++s) cacc = fmaf(e_lds[s], xp[(size_t)s * D_], cacc);
  ws_c[bid * D_ + tid] = cacc;
}

// Kernel 2 (fused combine+weights): grid B_ (64), 1024 thr.  (R14 verbatim)
__global__ __launch_bounds__(1024)
void k_epi(const float* __restrict__ ws_m, const float* __restrict__ ws_l,
           const float* __restrict__ ws_c, const float* __restrict__ ws_scores,
           float* __restrict__ out_ctx, float* __restrict__ out_w) {
  __shared__ float fac[BLKS_PER_B];
  __shared__ float MLs[2];
  const int b = blockIdx.x, tid = threadIdx.x;

  if (tid < 64) {
    float m = ws_m[b * BLKS_PER_B + tid];
    float l = ws_l[b * BLKS_PER_B + tid];
    float M = m;
#pragma unroll
    for (int o = 32; o >= 1; o >>= 1) M = fmaxf(M, __shfl_xor(M, o));
    float f = __expf(m - M);
    fac[tid] = f;
    float L = l * f;
#pragma unroll
    for (int o = 32; o >= 1; o >>= 1) L += __shfl_xor(L, o);
    if (tid == 0) { MLs[0] = M; MLs[1] = L; }
  }
  __syncthreads();
  const float M = MLs[0], L = MLs[1];
  const float invL = 1.0f / L;

  if (tid < D_) {
    float c = 0.f;
#pragma unroll 8
    for (int i = 0; i < BLKS_PER_B; ++i)
      c = fmaf(fac[i], ws_c[(size_t)(b * BLKS_PER_B + i) * D_ + tid], c);
    out_ctx[b * D_ + tid] = c * invL;
  }
#pragma unroll
  for (int r = 0; r < 4; ++r) {
    int s = r * 1024 + tid;
    out_w[b * S_ + s] = __expf(ws_scores[b * S_ + s] - M) * invL;
  }
}

extern "C" void kernel_launch(void* const* d_in, const int* in_sizes, int n_in,
                              void* d_out, int out_size, void* d_ws, size_t ws_size,
                              hipStream_t stream) {
  (void)in_sizes; (void)n_in; (void)out_size; (void)ws_size;
  const float* x    = (const float*)d_in[0];
  const float* W    = (const float*)d_in[1];
  const float* bias = (const float*)d_in[2];
  const float* u    = (const float*)d_in[3];
  float* out_ctx = (float*)d_out;                 // [64,256]
  float* out_w   = (float*)d_out + B_ * D_;       // [64,4096]

  char* ws = (char*)d_ws;
  short* wt        = (short*)(ws + 0);            // 131072 B
  float* ws_scores = (float*)(ws + 131072);       // 1048576 B
  float* ws_m      = (float*)(ws + 1179648);      // 16384 B
  float* ws_l      = (float*)(ws + 1196032);      // 16384 B
  float* ws_c      = (float*)(ws + 1212416);      // 4194304 B

  hipLaunchKernelGGL(k_pack, dim3(16), dim3(1024), 0, stream, W, wt);
  hipLaunchKernelGGL(k_scores, dim3(NBLK), dim3(256), 0, stream,
                     x, wt, bias, u, ws_scores, ws_m, ws_l, ws_c);
  hipLaunchKernelGGL(k_epi, dim3(B_), dim3(1024), 0, stream,
                     ws_m, ws_l, ws_c, ws_scores, out_ctx, out_w);
}

// Round 18
// 112.319 us; speedup vs baseline: 1.0090x; 1.0077x over previous
//
#include <hip/hip_runtime.h>
#include <hip/hip_bf16.h>
#include <cstdint>
#include <cstddef>

// Problem constants
#define B_ 64
#define S_ 4096
#define D_ 256
#define BM 64                   // rows per block (4 waves x 16 rows)
#define BK 32                   // k-step
#define NBLK (B_ * S_ / BM)     // 4096
#define BLKS_PER_B (S_ / BM)    // 64

typedef __attribute__((ext_vector_type(8))) short short8;
typedef __attribute__((ext_vector_type(4))) float f32x4;
typedef __attribute__((ext_vector_type(4))) float f4;

__device__ __forceinline__ short f2bf(float f) {
  union { float f; uint32_t u; } v; v.f = f;
  uint32_t r = v.u + 0x7FFFu + ((v.u >> 16) & 1u);   // RNE
  return (short)(r >> 16);
}

__device__ __forceinline__ short f2bf_i(float f) {
  // compiler-visible RNE convert (no inline asm; R17-proven)
  union { __hip_bfloat16 b; short s; } v;
  v.b = __float2bfloat16(f);
  return v.s;
}

__device__ __forceinline__ float fast_tanh(float z) {
  // tanh(z) = 1 - 2*rcp(e^{2z}+1); overflow-safe; rcp form PASSED R4/5/6/14/17
  return 1.0f - 2.0f * __builtin_amdgcn_rcpf(__expf(2.0f * z) + 1.0f);
}

__device__ __forceinline__ void gload_lds16(const short* g, short* l) {
  __builtin_amdgcn_global_load_lds(
      (const __attribute__((address_space(1))) int*)(g),
      (__attribute__((address_space(3))) int*)(l), 16, 0, 0);
}

// Kernel 0: FRAG-PACKED Wt. Output order: [kc][p][j] with p = nf*64+gr*16+cl,
// holding bf16(W[k][n]) for n = nf*16+cl, k = kc*32+gr*8+j.
// => stage source is linear in thread id; LDS B-read is lane-linear 1KB
// (conflict-free by construction). grid 64, 1024 thr, coalesced W reads.
__global__ void k_pack(const float* __restrict__ W, short* __restrict__ wt) {
  int idx = blockIdx.x * 1024 + threadIdx.x;   // 65536 elements
  int n = idx & 255, k = idx >> 8;             // coalesced read of row k
  int out = (k >> 5) * 8192 +
            (((n >> 4) * 64 + ((k >> 3) & 3) * 16 + (n & 15)) << 3) + (k & 7);
  wt[out] = f2bf(W[k * 256 + n]);
}

// ---- k_scores helper macros (R17-proven pipeline) ---------------------------
#define WAITV(N) asm volatile("s_waitcnt vmcnt(" #N ")" ::: "memory")
#define FENCE()  asm volatile("" ::: "memory")

// Stage B k-step KC into lsB[BUF]: 16 KB, 4 x global_load_lds(16B) per thread.
// Source is LINEAR (frag-packed wt) -> fully coalesced 16KB burst from L2.
#define STAGE(BUF, KC)                                                        \
  {                                                                           \
    _Pragma("unroll")                                                         \
    for (int i_ = 0; i_ < 4; ++i_) {                                          \
      int c_ = i_ * 256 + tid;                                                \
      gload_lds16(wt + (KC) * 8192 + c_ * 8, &lsB[BUF][c_ * 8]);              \
    }                                                                         \
  }

// One pipelined K-step (R17 structure; SINGLE DELTA: conflict-free B read —
// lane-linear 1KB per fragment): stage(K+1), issue A(K+2), counted vmcnt,
// barriers, cvt A(K), 16 MFMAs.
#define ITER(KC, VM, SCA, SCB, SLA, SLB, DOSTAGE, DOLOAD)                     \
  {                                                                           \
    if (DOSTAGE) STAGE(((KC) + 1) & 1, (KC) + 1);                             \
    if (DOLOAD) {                                                             \
      SLA = *(const f4*)(xrow + ((KC) + 2) * 32);                             \
      SLB = *(const f4*)(xrow + ((KC) + 2) * 32 + 4);                         \
    }                                                                         \
    WAITV(VM);                                                                \
    asm volatile("s_waitcnt lgkmcnt(0)" ::: "memory");                        \
    __builtin_amdgcn_sched_barrier(0);                                        \
    __builtin_amdgcn_s_barrier();                                             \
    FENCE();                                                                  \
    short8 fr_;                                                               \
    fr_[0]=f2bf_i(SCA[0]); fr_[1]=f2bf_i(SCA[1]); fr_[2]=f2bf_i(SCA[2]); fr_[3]=f2bf_i(SCA[3]); \
    fr_[4]=f2bf_i(SCB[0]); fr_[5]=f2bf_i(SCB[1]); fr_[6]=f2bf_i(SCB[2]); fr_[7]=f2bf_i(SCB[3]); \
    _Pragma("unroll")                                                         \
    for (int nf_ = 0; nf_ < 16; ++nf_) {                                      \
      short8 bfr_ = *(const short8*)&lsB[(KC) & 1][nf_ * 512 + boff];         \
      acc[nf_] = __builtin_amdgcn_mfma_f32_16x16x32_bf16(fr_, bfr_, acc[nf_], 0, 0, 0); \
    }                                                                         \
    FENCE();                                                                  \
    __builtin_amdgcn_s_barrier();                                             \
    FENCE();                                                                  \
  }

// Kernel 1: fused GEMM(x@W)+tanh+dot(u) -> scores; per-block softmax partials
// (m, l) and context partial. grid NBLK, 256 thr (4 waves, 16 rows each).
// B double-buffered in LDS, counted-vmcnt pipeline (R8/R14/R17 schedule).
__global__ __launch_bounds__(256, 3)
void k_scores(const float* __restrict__ x, const short* __restrict__ wt,
              const float* __restrict__ bias, const float* __restrict__ u,
              float* __restrict__ ws_scores, float* __restrict__ ws_m,
              float* __restrict__ ws_l, float* __restrict__ ws_c) {
  __shared__ __align__(16) short lsB[2][D_ * BK];   // 2 x 16 KB, frag-packed
  __shared__ __align__(8) float bu[D_ * 2];         // (bias, u) pairs
  __shared__ float score_lds[BM];
  __shared__ float e_lds[BM];
  __shared__ float red_lds[1];

  const int tid  = threadIdx.x;
  const int bid  = blockIdx.x;
  const int m0   = bid * BM;
  const int lane = tid & 63;
  const int wv   = tid >> 6;       // 0..3 : 16-row group
  const int cl   = lane & 15;
  const int gr   = lane >> 4;      // 0..3
  const int boff = lane * 8;       // B-read: lane-linear 16B slots (no conflicts)

  // (bias,u) first: compiler drains their loads before the ds_write, keeping
  // the vmcnt queue empty when the pipelined loads start.  (R17 verbatim)
  bu[tid * 2]     = bias[tid];
  bu[tid * 2 + 1] = u[tid];

  f32x4 acc[16];
#pragma unroll
  for (int j = 0; j < 16; ++j) acc[j] = (f32x4){0.f, 0.f, 0.f, 0.f};

  const float* xrow = x + (size_t)(m0 + wv * 16 + cl) * D_ + gr * 8;

  // Prologue: queue = A(0)[2], stage(0)[4], A(1)[2]
  f4 s0a, s0b, s1a, s1b, s2a, s2b;
  s0a = *(const f4*)(xrow);       s0b = *(const f4*)(xrow + 4);
  STAGE(0, 0);
  s1a = *(const f4*)(xrow + 32);  s1b = *(const f4*)(xrow + 36);

  // Steady state: 8 outstanding (4 stage + 2+2 A) stay in flight across waits.
  ITER(0, 8, s0a, s0b, s2a, s2b, 1, 1)
  ITER(1, 8, s1a, s1b, s0a, s0b, 1, 1)
  ITER(2, 8, s2a, s2b, s1a, s1b, 1, 1)
  ITER(3, 8, s0a, s0b, s2a, s2b, 1, 1)
  ITER(4, 8, s1a, s1b, s0a, s0b, 1, 1)
  ITER(5, 8, s2a, s2b, s1a, s1b, 1, 1)
  ITER(6, 6, s0a, s0b, s0a, s0b, 1, 0)
  ITER(7, 0, s1a, s1b, s0a, s0b, 0, 0)

  // Epilogue: score[row] = sum_n tanh(acc[row][n] + b[n]) * u[n]  (R17 verbatim)
  float p0 = 0.f, p1 = 0.f, p2 = 0.f, p3 = 0.f;
#pragma unroll
  for (int nf = 0; nf < 16; ++nf) {
    float bb = bu[(nf * 16 + cl) * 2];
    float uu = bu[(nf * 16 + cl) * 2 + 1];
    p0 += fast_tanh(acc[nf][0] + bb) * uu;
    p1 += fast_tanh(acc[nf][1] + bb) * uu;
    p2 += fast_tanh(acc[nf][2] + bb) * uu;
    p3 += fast_tanh(acc[nf][3] + bb) * uu;
  }
#pragma unroll
  for (int m = 1; m < 16; m <<= 1) {
    p0 += __shfl_xor(p0, m);
    p1 += __shfl_xor(p1, m);
    p2 += __shfl_xor(p2, m);
    p3 += __shfl_xor(p3, m);
  }
  if (cl == 0) {
    int r = wv * 16 + gr * 4;
    score_lds[r + 0] = p0;
    score_lds[r + 1] = p1;
    score_lds[r + 2] = p2;
    score_lds[r + 3] = p3;
    ws_scores[m0 + r + 0] = p0;
    ws_scores[m0 + r + 1] = p1;
    ws_scores[m0 + r + 2] = p2;
    ws_scores[m0 + r + 3] = p3;
  }
  __syncthreads();
  // block max over 64 scores (wave 0)
  if (tid < 64) {
    float v = score_lds[tid];
#pragma unroll
    for (int m = 32; m >= 1; m >>= 1) v = fmaxf(v, __shfl_xor(v, m));
    if (tid == 0) red_lds[0] = v;
  }
  __syncthreads();
  float mb = red_lds[0];
  if (tid < BM) e_lds[tid] = __expf(score_lds[tid] - mb);
  __syncthreads();
  if (tid < 64) {
    float v = e_lds[tid];
#pragma unroll
    for (int m = 32; m >= 1; m >>= 1) v += __shfl_xor(v, m);
    if (tid == 0) { ws_m[bid] = mb; ws_l[bid] = v; }
  }
  // context partial: thread owns column d = tid; x tile is L1/L2-hot
  float cacc = 0.f;
  const float* xp = x + (size_t)m0 * D_ + tid;
#pragma unroll 4
  for (int s = 0; s < BM; ++s) cacc = fmaf(e_lds[s], xp[(size_t)s * D_], cacc);
  ws_c[bid * D_ + tid] = cacc;
}

// Kernel 2 (fused combine+weights): grid B_ (64), 1024 thr.  (R17 verbatim)
__global__ __launch_bounds__(1024)
void k_epi(const float* __restrict__ ws_m, const float* __restrict__ ws_l,
           const float* __restrict__ ws_c, const float* __restrict__ ws_scores,
           float* __restrict__ out_ctx, float* __restrict__ out_w) {
  __shared__ float fac[BLKS_PER_B];
  __shared__ float MLs[2];
  const int b = blockIdx.x, tid = threadIdx.x;

  if (tid < 64) {
    float m = ws_m[b * BLKS_PER_B + tid];
    float l = ws_l[b * BLKS_PER_B + tid];
    float M = m;
#pragma unroll
    for (int o = 32; o >= 1; o >>= 1) M = fmaxf(M, __shfl_xor(M, o));
    float f = __expf(m - M);
    fac[tid] = f;
    float L = l * f;
#pragma unroll
    for (int o = 32; o >= 1; o >>= 1) L += __shfl_xor(L, o);
    if (tid == 0) { MLs[0] = M; MLs[1] = L; }
  }
  __syncthreads();
  const float M = MLs[0], L = MLs[1];
  const float invL = 1.0f / L;

  if (tid < D_) {
    float c = 0.f;
#pragma unroll 8
    for (int i = 0; i < BLKS_PER_B; ++i)
      c = fmaf(fac[i], ws_c[(size_t)(b * BLKS_PER_B + i) * D_ + tid], c);
    out_ctx[b * D_ + tid] = c * invL;
  }
#pragma unroll
  for (int r = 0; r < 4; ++r) {
    int s = r * 1024 + tid;
    out_w[b * S_ + s] = __expf(ws_scores[b * S_ + s] - M) * invL;
  }
}

extern "C" void kernel_launch(void* const* d_in, const int* in_sizes, int n_in,
                              void* d_out, int out_size, void* d_ws, size_t ws_size,
                              hipStream_t stream) {
  (void)in_sizes; (void)n_in; (void)out_size; (void)ws_size;
  const float* x    = (const float*)d_in[0];
  const float* W    = (const float*)d_in[1];
  const float* bias = (const float*)d_in[2];
  const float* u    = (const float*)d_in[3];
  float* out_ctx = (float*)d_out;                 // [64,256]
  float* out_w   = (float*)d_out + B_ * D_;       // [64,4096]

  char* ws = (char*)d_ws;
  short* wt        = (short*)(ws + 0);            // 131072 B (frag-packed)
  float* ws_scores = (float*)(ws + 131072);       // 1048576 B
  float* ws_m      = (float*)(ws + 1179648);      // 16384 B
  float* ws_l      = (float*)(ws + 1196032);      // 16384 B
  float* ws_c      = (float*)(ws + 1212416);      // 4194304 B

  hipLaunchKernelGGL(k_pack, dim3(64), dim3(1024), 0, stream, W, wt);
  hipLaunchKernelGGL(k_scores, dim3(NBLK), dim3(256), 0, stream,
                     x, wt, bias, u, ws_scores, ws_m, ws_l, ws_c);
  hipLaunchKernelGGL(k_epi, dim3(B_), dim3(1024), 0, stream,
                     ws_m, ws_l, ws_c, ws_scores, out_ctx, out_w);
}

// Round 19
// 106.225 us; speedup vs baseline: 1.0669x; 1.0574x over previous
//
#include <hip/hip_runtime.h>
#include <hip/hip_bf16.h>
#include <cstdint>
#include <cstddef>

// Problem constants
#define B_ 64
#define S_ 4096
#define D_ 256
#define BM 64                   // rows per block (4 waves x 16 rows)
#define BK 32                   // k-step
#define NBLK (B_ * S_ / BM)     // 4096
#define BLKS_PER_B (S_ / BM)    // 64

typedef __attribute__((ext_vector_type(8))) short short8;
typedef __attribute__((ext_vector_type(4))) float f32x4;
typedef __attribute__((ext_vector_type(4))) float f4;

__device__ __forceinline__ short f2bf(float f) {
  union { float f; uint32_t u; } v; v.f = f;
  uint32_t r = v.u + 0x7FFFu + ((v.u >> 16) & 1u);   // RNE
  return (short)(r >> 16);
}

__device__ __forceinline__ short f2bf_i(float f) {
  // compiler-visible RNE convert (no inline asm; R17/R18-proven)
  union { __hip_bfloat16 b; short s; } v;
  v.b = __float2bfloat16(f);
  return v.s;
}

__device__ __forceinline__ float fast_tanh(float z) {
  // tanh(z) = 1 - 2*rcp(e^{2z}+1); overflow-safe; rcp form PASSED R4/5/6/14/17/18
  return 1.0f - 2.0f * __builtin_amdgcn_rcpf(__expf(2.0f * z) + 1.0f);
}

__device__ __forceinline__ void gload_lds16(const short* g, short* l) {
  __builtin_amdgcn_global_load_lds(
      (const __attribute__((address_space(1))) int*)(g),
      (__attribute__((address_space(3))) int*)(l), 16, 0, 0);
}

// Kernel 0: FRAG-PACKED Wt (R18 layout). Output order: [kc][p][j] with
// p = nf*64+gr*16+cl, holding bf16(W[k][n]) for n = nf*16+cl, k = kc*32+gr*8+j.
// => stage source linear in tid; LDS B-read lane-linear 1KB (conflict-free).
__global__ void k_pack(const float* __restrict__ W, short* __restrict__ wt) {
  int idx = blockIdx.x * 1024 + threadIdx.x;   // 65536 elements
  int n = idx & 255, k = idx >> 8;             // coalesced read of row k
  int out = (k >> 5) * 8192 +
            (((n >> 4) * 64 + ((k >> 3) & 3) * 16 + (n & 15)) << 3) + (k & 7);
  wt[out] = f2bf(W[k * 256 + n]);
}

// ---- k_scores helper macros (R18-proven pipeline) ---------------------------
#define WAITV(N) asm volatile("s_waitcnt vmcnt(" #N ")" ::: "memory")
#define FENCE()  asm volatile("" ::: "memory")

// Stage B k-step KC into lsB[BUF]: 16 KB, 4 x global_load_lds(16B) per thread.
// Source is LINEAR (frag-packed wt) -> fully coalesced 16KB burst from L2.
#define STAGE(BUF, KC)                                                        \
  {                                                                           \
    _Pragma("unroll")                                                         \
    for (int i_ = 0; i_ < 4; ++i_) {                                          \
      int c_ = i_ * 256 + tid;                                                \
      gload_lds16(wt + (KC) * 8192 + c_ * 8, &lsB[BUF][c_ * 8]);              \
    }                                                                         \
  }

// One pipelined K-step (R18 verbatim): stage(K+1), issue A(K+2), counted
// vmcnt, barriers, cvt A(K), 16 MFMAs (lane-linear conflict-free B reads).
#define ITER(KC, VM, SCA, SCB, SLA, SLB, DOSTAGE, DOLOAD)                     \
  {                                                                           \
    if (DOSTAGE) STAGE(((KC) + 1) & 1, (KC) + 1);                             \
    if (DOLOAD) {                                                             \
      SLA = *(const f4*)(xrow + ((KC) + 2) * 32);                             \
      SLB = *(const f4*)(xrow + ((KC) + 2) * 32 + 4);                         \
    }                                                                         \
    WAITV(VM);                                                                \
    asm volatile("s_waitcnt lgkmcnt(0)" ::: "memory");                        \
    __builtin_amdgcn_sched_barrier(0);                                        \
    __builtin_amdgcn_s_barrier();                                             \
    FENCE();                                                                  \
    short8 fr_;                                                               \
    fr_[0]=f2bf_i(SCA[0]); fr_[1]=f2bf_i(SCA[1]); fr_[2]=f2bf_i(SCA[2]); fr_[3]=f2bf_i(SCA[3]); \
    fr_[4]=f2bf_i(SCB[0]); fr_[5]=f2bf_i(SCB[1]); fr_[6]=f2bf_i(SCB[2]); fr_[7]=f2bf_i(SCB[3]); \
    _Pragma("unroll")                                                         \
    for (int nf_ = 0; nf_ < 16; ++nf_) {                                      \
      short8 bfr_ = *(const short8*)&lsB[(KC) & 1][nf_ * 512 + boff];         \
      acc[nf_] = __builtin_amdgcn_mfma_f32_16x16x32_bf16(fr_, bfr_, acc[nf_], 0, 0, 0); \
    }                                                                         \
    FENCE();                                                                  \
    __builtin_amdgcn_s_barrier();                                             \
    FENCE();                                                                  \
  }

// Kernel 1: fused GEMM(x@W)+tanh+dot(u) -> scores; per-block softmax partials
// (m, l) and context partial. grid NBLK, 256 thr (4 waves, 16 rows each).
// SINGLE DELTA vs R18: __launch_bounds__(256,4) -> 4 resident blocks/CU
// (128 unified regs = 64 arch + 64 acc fits exactly; LDS 35.8KB x4 < 160KB).
__global__ __launch_bounds__(256, 4)
void k_scores(const float* __restrict__ x, const short* __restrict__ wt,
              const float* __restrict__ bias, const float* __restrict__ u,
              float* __restrict__ ws_scores, float* __restrict__ ws_m,
              float* __restrict__ ws_l, float* __restrict__ ws_c) {
  __shared__ __align__(16) short lsB[2][D_ * BK];   // 2 x 16 KB, frag-packed
  __shared__ __align__(8) float bu[D_ * 2];         // (bias, u) pairs
  __shared__ float score_lds[BM];
  __shared__ float e_lds[BM];
  __shared__ float red_lds[1];

  const int tid  = threadIdx.x;
  const int bid  = blockIdx.x;
  const int m0   = bid * BM;
  const int lane = tid & 63;
  const int wv   = tid >> 6;       // 0..3 : 16-row group
  const int cl   = lane & 15;
  const int gr   = lane >> 4;      // 0..3
  const int boff = lane * 8;       // B-read: lane-linear 16B slots (no conflicts)

  // (bias,u) first: compiler drains their loads before the ds_write, keeping
  // the vmcnt queue empty when the pipelined loads start.  (R18 verbatim)
  bu[tid * 2]     = bias[tid];
  bu[tid * 2 + 1] = u[tid];

  f32x4 acc[16];
#pragma unroll
  for (int j = 0; j < 16; ++j) acc[j] = (f32x4){0.f, 0.f, 0.f, 0.f};

  const float* xrow = x + (size_t)(m0 + wv * 16 + cl) * D_ + gr * 8;

  // Prologue: queue = A(0)[2], stage(0)[4], A(1)[2]
  f4 s0a, s0b, s1a, s1b, s2a, s2b;
  s0a = *(const f4*)(xrow);       s0b = *(const f4*)(xrow + 4);
  STAGE(0, 0);
  s1a = *(const f4*)(xrow + 32);  s1b = *(const f4*)(xrow + 36);

  // Steady state: 8 outstanding (4 stage + 2+2 A) stay in flight across waits.
  ITER(0, 8, s0a, s0b, s2a, s2b, 1, 1)
  ITER(1, 8, s1a, s1b, s0a, s0b, 1, 1)
  ITER(2, 8, s2a, s2b, s1a, s1b, 1, 1)
  ITER(3, 8, s0a, s0b, s2a, s2b, 1, 1)
  ITER(4, 8, s1a, s1b, s0a, s0b, 1, 1)
  ITER(5, 8, s2a, s2b, s1a, s1b, 1, 1)
  ITER(6, 6, s0a, s0b, s0a, s0b, 1, 0)
  ITER(7, 0, s1a, s1b, s0a, s0b, 0, 0)

  // Epilogue: score[row] = sum_n tanh(acc[row][n] + b[n]) * u[n]  (R18 verbatim)
  float p0 = 0.f, p1 = 0.f, p2 = 0.f, p3 = 0.f;
#pragma unroll
  for (int nf = 0; nf < 16; ++nf) {
    float bb = bu[(nf * 16 + cl) * 2];
    float uu = bu[(nf * 16 + cl) * 2 + 1];
    p0 += fast_tanh(acc[nf][0] + bb) * uu;
    p1 += fast_tanh(acc[nf][1] + bb) * uu;
    p2 += fast_tanh(acc[nf][2] + bb) * uu;
    p3 += fast_tanh(acc[nf][3] + bb) * uu;
  }
#pragma unroll
  for (int m = 1; m < 16; m <<= 1) {
    p0 += __shfl_xor(p0, m);
    p1 += __shfl_xor(p1, m);
    p2 += __shfl_xor(p2, m);
    p3 += __shfl_xor(p3, m);
  }
  if (cl == 0) {
    int r = wv * 16 + gr * 4;
    score_lds[r + 0] = p0;
    score_lds[r + 1] = p1;
    score_lds[r + 2] = p2;
    score_lds[r + 3] = p3;
    ws_scores[m0 + r + 0] = p0;
    ws_scores[m0 + r + 1] = p1;
    ws_scores[m0 + r + 2] = p2;
    ws_scores[m0 + r + 3] = p3;
  }
  __syncthreads();
  // block max over 64 scores (wave 0)
  if (tid < 64) {
    float v = score_lds[tid];
#pragma unroll
    for (int m = 32; m >= 1; m >>= 1) v = fmaxf(v, __shfl_xor(v, m));
    if (tid == 0) red_lds[0] = v;
  }
  __syncthreads();
  float mb = red_lds[0];
  if (tid < BM) e_lds[tid] = __expf(score_lds[tid] - mb);
  __syncthreads();
  if (tid < 64) {
    float v = e_lds[tid];
#pragma unroll
    for (int m = 32; m >= 1; m >>= 1) v += __shfl_xor(v, m);
    if (tid == 0) { ws_m[bid] = mb; ws_l[bid] = v; }
  }
  // context partial: thread owns column d = tid; x tile is L1/L2-hot
  float cacc = 0.f;
  const float* xp = x + (size_t)m0 * D_ + tid;
#pragma unroll 4
  for (int s = 0; s < BM; ++s) cacc = fmaf(e_lds[s], xp[(size_t)s * D_], cacc);
  ws_c[bid * D_ + tid] = cacc;
}

// Kernel 2 (fused combine+weights): grid B_ (64), 1024 thr.  (R18 verbatim)
__global__ __launch_bounds__(1024)
void k_epi(const float* __restrict__ ws_m, const float* __restrict__ ws_l,
           const float* __restrict__ ws_c, const float* __restrict__ ws_scores,
           float* __restrict__ out_ctx, float* __restrict__ out_w) {
  __shared__ float fac[BLKS_PER_B];
  __shared__ float MLs[2];
  const int b = blockIdx.x, tid = threadIdx.x;

  if (tid < 64) {
    float m = ws_m[b * BLKS_PER_B + tid];
    float l = ws_l[b * BLKS_PER_B + tid];
    float M = m;
#pragma unroll
    for (int o = 32; o >= 1; o >>= 1) M = fmaxf(M, __shfl_xor(M, o));
    float f = __expf(m - M);
    fac[tid] = f;
    float L = l * f;
#pragma unroll
    for (int o = 32; o >= 1; o >>= 1) L += __shfl_xor(L, o);
    if (tid == 0) { MLs[0] = M; MLs[1] = L; }
  }
  __syncthreads();
  const float M = MLs[0], L = MLs[1];
  const float invL = 1.0f / L;

  if (tid < D_) {
    float c = 0.f;
#pragma unroll 8
    for (int i = 0; i < BLKS_PER_B; ++i)
      c = fmaf(fac[i], ws_c[(size_t)(b * BLKS_PER_B + i) * D_ + tid], c);
    out_ctx[b * D_ + tid] = c * invL;
  }
#pragma unroll
  for (int r = 0; r < 4; ++r) {
    int s = r * 1024 + tid;
    out_w[b * S_ + s] = __expf(ws_scores[b * S_ + s] - M) * invL;
  }
}

extern "C" void kernel_launch(void* const* d_in, const int* in_sizes, int n_in,
                              void* d_out, int out_size, void* d_ws, size_t ws_size,
                              hipStream_t stream) {
  (void)in_sizes; (void)n_in; (void)out_size; (void)ws_size;
  const float* x    = (const float*)d_in[0];
  const float* W    = (const float*)d_in[1];
  const float* bias = (const float*)d_in[2];
  const float* u    = (const float*)d_in[3];
  float* out_ctx = (float*)d_out;                 // [64,256]
  float* out_w   = (float*)d_out + B_ * D_;       // [64,4096]

  char* ws = (char*)d_ws;
  short* wt        = (short*)(ws + 0);            // 131072 B (frag-packed)
  float* ws_scores = (float*)(ws + 131072);       // 1048576 B
  float* ws_m      = (float*)(ws + 1179648);      // 16384 B
  float* ws_l      = (float*)(ws + 1196032);      // 16384 B
  float* ws_c      = (float*)(ws + 1212416);      // 4194304 B

  hipLaunchKernelGGL(k_pack, dim3(64), dim3(1024), 0, stream, W, wt);
  hipLaunchKernelGGL(k_scores, dim3(NBLK), dim3(256), 0, stream,
                     x, wt, bias, u, ws_scores, ws_m, ws_l, ws_c);
  hipLaunchKernelGGL(k_epi, dim3(B_), dim3(1024), 0, stream,
                     ws_m, ws_l, ws_c, ws_scores, out_ctx, out_w);
}